// Round 1
// 1268.930 us; speedup vs baseline: 1.7117x; 1.7117x over previous
//
#include <hip/hip_runtime.h>
#include <hip/hip_bf16.h>

// Shapes (fixed by harness)
#define B_  8
#define TN_ 128
#define C_  2048
#define H_  16
#define TP_ 2048
#define D_  128
#define TT_ 2176   // TP_ + TN_
#define M_  1024   // B_*TN_

typedef __attribute__((ext_vector_type(8))) short bf16x8;   // 8 bf16 (4 VGPRs)
typedef __attribute__((ext_vector_type(4))) float f32x4;    // MFMA accumulator

static __device__ __forceinline__ unsigned short f2bu(float f) {
    unsigned int u = __float_as_uint(f);
    unsigned int r = (u + 0x7FFFu + ((u >> 16) & 1u)) >> 16;  // RNE (inputs finite)
    return (unsigned short)r;
}

// ---------------------------------------------------------------------------
// Kernel 1: copy K_past/V_past (fp32) into first TP_ rows of K_out/V_out.
// ---------------------------------------------------------------------------
__global__ __launch_bounds__(256) void copy_past_kernel(
    const float* __restrict__ Kp, const float* __restrict__ Vp,
    float* __restrict__ Ko, float* __restrict__ Vo)
{
    const long long NV = (long long)B_ * H_ * TP_ * D_ / 4;  // 8388608 float4 per tensor
    long long stride = (long long)gridDim.x * blockDim.x;
    for (long long idx = (long long)blockIdx.x * blockDim.x + threadIdx.x;
         idx < 2 * NV; idx += stride) {
        int sel = idx >= NV;
        long long v = sel ? idx - NV : idx;
        long long bh = v >> 16;        // / (TP_*D_/4 = 65536)
        long long r  = v & 65535;
        const float4* s = (const float4*)((sel ? Vp : Kp) + (bh << 18)) + r;
        float4* d = (float4*)((sel ? Vo : Ko) + bh * (long long)(TT_ * D_)) + r;
        *d = *s;
    }
}

// ---------------------------------------------------------------------------
// Kernel 2: tiled fp32 GEMM  out[1024,2048] = A[1024,2048] @ W[2048,2048] + bias
// (unchanged from verified version)
// ---------------------------------------------------------------------------
__global__ __launch_bounds__(256) void gemm_kernel(
    const float* __restrict__ A,
    const float* __restrict__ W,
    const float* __restrict__ bias,
    float* __restrict__ out,
    int scatter)
{
    __shared__ float As[32][68];   // [k][m]
    __shared__ float Bs[32][68];   // [k][n]
    const int tid = threadIdx.x;
    const int m0 = blockIdx.y * 64, n0 = blockIdx.x * 64;
    const int ty = tid >> 4, tx = tid & 15;
    const int arow = tid >> 2, akg = (tid & 3) * 8;
    float acc[4][4] = {{0.f}};

    for (int kt = 0; kt < C_; kt += 32) {
        const float4* ap = (const float4*)(A + (long long)(m0 + arow) * C_ + kt + akg);
        float4 a0 = ap[0], a1 = ap[1];
        As[akg + 0][arow] = a0.x; As[akg + 1][arow] = a0.y;
        As[akg + 2][arow] = a0.z; As[akg + 3][arow] = a0.w;
        As[akg + 4][arow] = a1.x; As[akg + 5][arow] = a1.y;
        As[akg + 6][arow] = a1.z; As[akg + 7][arow] = a1.w;
        #pragma unroll
        for (int it = 0; it < 2; ++it) {
            int kl = (tid >> 4) + it * 16;
            *(float4*)&Bs[kl][tx * 4] =
                *(const float4*)(W + (long long)(kt + kl) * C_ + n0 + tx * 4);
        }
        __syncthreads();
        #pragma unroll
        for (int kk = 0; kk < 32; ++kk) {
            float4 a = *(const float4*)&As[kk][ty * 4];
            float4 b = *(const float4*)&Bs[kk][tx * 4];
            acc[0][0] += a.x * b.x; acc[0][1] += a.x * b.y; acc[0][2] += a.x * b.z; acc[0][3] += a.x * b.w;
            acc[1][0] += a.y * b.x; acc[1][1] += a.y * b.y; acc[1][2] += a.y * b.z; acc[1][3] += a.y * b.w;
            acc[2][0] += a.z * b.x; acc[2][1] += a.z * b.y; acc[2][2] += a.z * b.z; acc[2][3] += a.z * b.w;
            acc[3][0] += a.w * b.x; acc[3][1] += a.w * b.y; acc[3][2] += a.w * b.z; acc[3][3] += a.w * b.w;
        }
        __syncthreads();
    }
    float bb[4];
    #pragma unroll
    for (int j = 0; j < 4; ++j) bb[j] = bias[n0 + tx * 4 + j];
    #pragma unroll
    for (int i = 0; i < 4; ++i) {
        int m = m0 + ty * 4 + i;
        #pragma unroll
        for (int j = 0; j < 4; ++j) {
            int n = n0 + tx * 4 + j;
            float r = acc[i][j] + bb[j];
            if (!scatter) {
                out[(long long)m * C_ + n] = r;
            } else {
                int b2 = m >> 7, t = m & 127, h2 = n >> 7, d2 = n & 127;
                out[(((long long)(b2 * H_ + h2)) * TT_ + TP_ + t) * D_ + d2] = r;
            }
        }
    }
}

// ---------------------------------------------------------------------------
// Kernel 3: MFMA flash attention (bf16 inputs to matrix cores, fp32 accum).
// Block = (b,h, 64-query tile), 256 threads = 4 waves; wave w owns q rows
// [q0+16w, q0+16w+16). Per 64-key chunk:
//   K -> LDS row-major bf16, rows padded to 136 ushorts (272B = 17x16B:
//        fragment b128 reads land on distinct 16B slots, ~floor).
//   V -> LDS TRANSPOSED Vt[d][key] bf16, 8-key "oct" XOR-swizzled by (d>>3)&7
//        so both the ushort4 transpose-writes and the b128 B-fragment reads
//        are conflict-free (bank floor).
//   QK^T: mfma_f32_16x16x32_bf16, A = Q frags (in registers, loaded once),
//        B = K rows. C/D map: col(key)=lane&15, row(q)=(lane>>4)*4+reg.
//   Online softmax per lane (4 rows), row-reduce via shfl_xor 1/2/4/8.
//   P relayout to A-fragments via small per-wave padded LDS buffer.
//   PV: A = P frags, B = Vt rows (transpose-free b128 reads).
// ---------------------------------------------------------------------------
__global__ __launch_bounds__(256) void attn_mfma_kernel(
    const float* __restrict__ Qw,   // (1024, 2048): row b*128+t, col h*128+d
    const float* __restrict__ Kf,   // (B*H, 2176, 128) fp32
    const float* __restrict__ Vf,
    float* __restrict__ Ow,         // (1024, 2048)
    const int* __restrict__ poff)
{
    __shared__ __align__(16) unsigned short Ks[64][136];   // 17408 B
    __shared__ __align__(16) unsigned short Vt[128][72];   // 18432 B
    __shared__ __align__(16) unsigned short Pw[4][16][72]; //  9216 B

    const int tid = threadIdx.x;
    const int lane = tid & 63;
    const int w = tid >> 6;          // wave id 0..3
    const int lr = lane & 15;
    const int lg = lane >> 4;        // 0..3
    const int bh = blockIdx.x, b = bh >> 4, h = bh & 15;
    const int q0 = blockIdx.y * 64;
    const int off = *poff;
    const float scale = 0.08838834764831843f;  // 1/sqrt(128)

    // ---- Q A-fragments in registers: lane feeds row q=lr, dims kt*32+lg*8+0..7
    bf16x8 qf[4];
    {
        const float* qsrc = Qw + ((long long)(b * TN_ + q0 + w * 16 + lr)) * C_ + h * D_;
        #pragma unroll
        for (int kt = 0; kt < 4; ++kt) {
            const float4* p4 = (const float4*)(qsrc + kt * 32 + lg * 8);
            float4 x0 = p4[0], x1 = p4[1];
            union { unsigned short u[8]; bf16x8 v; } pk;
            pk.u[0] = f2bu(x0.x); pk.u[1] = f2bu(x0.y);
            pk.u[2] = f2bu(x0.z); pk.u[3] = f2bu(x0.w);
            pk.u[4] = f2bu(x1.x); pk.u[5] = f2bu(x1.y);
            pk.u[6] = f2bu(x1.z); pk.u[7] = f2bu(x1.w);
            qf[kt] = pk.v;
        }
    }

    const int skey = tid >> 2, sdg = (tid & 3) * 32;  // K staging: key row, dim group
    const int vd = tid & 127, vhalf = tid >> 7;       // V staging: dim, key half
    const int vswz = (vd >> 3) & 7;
    const int tq = q0 + w * 16 + lg * 4;              // this lane's D-row base (q)

    float m_r[4], l_r[4];
    f32x4 ov[8];
    #pragma unroll
    for (int r = 0; r < 4; ++r) { m_r[r] = -1e30f; l_r[r] = 0.f; }
    #pragma unroll
    for (int dt = 0; dt < 8; ++dt) ov[dt] = (f32x4){0.f, 0.f, 0.f, 0.f};

    const int upper = TP_ + q0 + 64;   // 64-aligned: no staging guards needed

    for (int kc = 0; kc < upper; kc += 64) {
        __syncthreads();   // prev chunk's PV reads done before restaging
        // ---- stage K chunk (row-major bf16, padded)
        {
            const float4* ksrc = (const float4*)(Kf + ((long long)bh * TT_ + kc + skey) * D_ + sdg);
            #pragma unroll
            for (int u = 0; u < 8; ++u) {
                float4 k4 = ksrc[u];
                ushort4 kp;
                kp.x = f2bu(k4.x); kp.y = f2bu(k4.y); kp.z = f2bu(k4.z); kp.w = f2bu(k4.w);
                *(ushort4*)&Ks[skey][sdg + u * 4] = kp;
            }
        }
        // ---- stage V chunk transposed: Vt[d][key], oct-XOR swizzle on key octets
        {
            const float* vsrc = Vf + ((long long)bh * TT_ + kc) * D_ + vd;
            #pragma unroll
            for (int j = 0; j < 8; ++j) {
                int k4 = vhalf * 32 + j * 4;
                float a0 = vsrc[(k4 + 0) * D_];
                float a1 = vsrc[(k4 + 1) * D_];
                float a2 = vsrc[(k4 + 2) * D_];
                float a3 = vsrc[(k4 + 3) * D_];
                ushort4 vp;
                vp.x = f2bu(a0); vp.y = f2bu(a1); vp.z = f2bu(a2); vp.w = f2bu(a3);
                int col = (((k4 >> 3) ^ vswz) << 3) + (k4 & 7);
                *(ushort4*)&Vt[vd][col] = vp;
            }
        }
        __syncthreads();

        // ---- QK^T: 4 key tiles x 4 k-steps
        f32x4 sa[4];
        #pragma unroll
        for (int n = 0; n < 4; ++n) {
            f32x4 acc = (f32x4){0.f, 0.f, 0.f, 0.f};
            #pragma unroll
            for (int kt = 0; kt < 4; ++kt) {
                bf16x8 kfrag = *(const bf16x8*)&Ks[n * 16 + lr][kt * 32 + lg * 8];
                acc = __builtin_amdgcn_mfma_f32_16x16x32_bf16(qf[kt], kfrag, acc, 0, 0, 0);
            }
            sa[n] = acc;
        }

        // ---- mask + scale (lane element (n,r): key=kc+n*16+lr, query=tq+r)
        float sv[4][4];
        #pragma unroll
        for (int n = 0; n < 4; ++n) {
            int kg = kc + n * 16 + lr;
            #pragma unroll
            for (int r = 0; r < 4; ++r) {
                bool okm = (kg < TP_) ? (kg <= off + tq + r) : (kg - TP_ <= tq + r);
                sv[n][r] = okm ? sa[n][r] * scale : -1e30f;
            }
        }

        // ---- online softmax per row; write P (bf16) to per-wave LDS
        #pragma unroll
        for (int r = 0; r < 4; ++r) {
            float mloc = fmaxf(fmaxf(sv[0][r], sv[1][r]), fmaxf(sv[2][r], sv[3][r]));
            #pragma unroll
            for (int dx = 1; dx < 16; dx <<= 1) mloc = fmaxf(mloc, __shfl_xor(mloc, dx));
            float mnew = fmaxf(m_r[r], mloc);
            float alpha = __expf(m_r[r] - mnew);   // first chunk: exp(-inf)=0
            float psum = 0.f;
            #pragma unroll
            for (int n = 0; n < 4; ++n) {
                float p = __expf(sv[n][r] - mnew); // masked: exp(-1e30)==0
                psum += p;
                Pw[w][lg * 4 + r][n * 16 + lr] = f2bu(p);
            }
            #pragma unroll
            for (int dx = 1; dx < 16; dx <<= 1) psum += __shfl_xor(psum, dx);
            m_r[r] = mnew;
            l_r[r] = l_r[r] * alpha + psum;
            #pragma unroll
            for (int dt = 0; dt < 8; ++dt) ov[dt][r] *= alpha;
        }

        // ---- PV: A = P fragments (row q=lr, keys lg*8+..), B = Vt rows
        bf16x8 pf0 = *(const bf16x8*)&Pw[w][lr][lg * 8];
        bf16x8 pf1 = *(const bf16x8*)&Pw[w][lr][32 + lg * 8];
        #pragma unroll
        for (int dt = 0; dt < 8; ++dt) {
            int d = dt * 16 + lr;
            int sw = (d >> 3) & 7;
            bf16x8 vf0 = *(const bf16x8*)&Vt[d][(lg ^ sw) << 3];
            ov[dt] = __builtin_amdgcn_mfma_f32_16x16x32_bf16(pf0, vf0, ov[dt], 0, 0, 0);
            bf16x8 vf1 = *(const bf16x8*)&Vt[d][((4 + lg) ^ sw) << 3];
            ov[dt] = __builtin_amdgcn_mfma_f32_16x16x32_bf16(pf1, vf1, ov[dt], 0, 0, 0);
        }
    }

    // ---- epilogue: normalize and store
    #pragma unroll
    for (int r = 0; r < 4; ++r) {
        float inv = 1.0f / l_r[r];
        float* dst = Ow + ((long long)(b * TN_ + tq + r)) * C_ + h * D_ + lr;
        #pragma unroll
        for (int dt = 0; dt < 8; ++dt) dst[dt * 16] = ov[dt][r] * inv;
    }
}

// ---------------------------------------------------------------------------
extern "C" void kernel_launch(void* const* d_in, const int* in_sizes, int n_in,
                              void* d_out, int out_size, void* d_ws, size_t ws_size,
                              hipStream_t stream)
{
    (void)in_sizes; (void)n_in; (void)out_size; (void)ws_size;
    const float* x  = (const float*)d_in[0];
    const float* Kp = (const float*)d_in[1];
    const float* Vp = (const float*)d_in[2];
    const float* Wq = (const float*)d_in[3];
    const float* bq = (const float*)d_in[4];
    const float* Wk = (const float*)d_in[5];
    const float* bk = (const float*)d_in[6];
    const float* Wv = (const float*)d_in[7];
    const float* bv = (const float*)d_in[8];
    const float* Wo = (const float*)d_in[9];
    const float* bo = (const float*)d_in[10];
    const int* poff = (const int*)d_in[11];

    float* out = (float*)d_out;
    float* Ko  = out + (long long)M_ * C_;                 // K output region
    float* Vo  = Ko + (long long)B_ * H_ * TT_ * D_;       // V output region

    float* Qws = (float*)d_ws;                             // 8 MB: Q (1024x2048 f32)
    float* Aws = Qws + (long long)M_ * C_;                 // 8 MB: attn out

    hipLaunchKernelGGL(copy_past_kernel, dim3(8192), dim3(256), 0, stream, Kp, Vp, Ko, Vo);
    dim3 gg(C_ / 64, M_ / 64);
    hipLaunchKernelGGL(gemm_kernel, gg, dim3(256), 0, stream, x, Wq, bq, Qws, 0);
    hipLaunchKernelGGL(gemm_kernel, gg, dim3(256), 0, stream, x, Wk, bk, Ko, 1);
    hipLaunchKernelGGL(gemm_kernel, gg, dim3(256), 0, stream, x, Wv, bv, Vo, 1);
    // grid (bh, qtile): blocks of the same bh are 128 apart in linear id
    // (128 % 8 == 0) -> same XCD -> K/V chunk re-reads hit the same L2.
    hipLaunchKernelGGL(attn_mfma_kernel, dim3(B_ * H_, TN_ / 64), dim3(256), 0, stream,
                       Qws, Ko, Vo, Aws, poff);
    hipLaunchKernelGGL(gemm_kernel, gg, dim3(256), 0, stream, Aws, Wo, bo, out, 0);
}

// Round 3
// 1076.616 us; speedup vs baseline: 2.0175x; 1.1786x over previous
//
#include <hip/hip_runtime.h>
#include <hip/hip_bf16.h>

// Shapes (fixed by harness)
#define B_  8
#define TN_ 128
#define C_  2048
#define H_  16
#define TP_ 2048
#define D_  128
#define TT_ 2176   // TP_ + TN_
#define M_  1024   // B_*TN_

typedef __attribute__((ext_vector_type(8))) short bf16x8;   // 8 bf16 (4 VGPRs)
typedef __attribute__((ext_vector_type(4))) float f32x4;    // MFMA accumulator

static __device__ __forceinline__ unsigned short f2bu(float f) {
    unsigned int u = __float_as_uint(f);
    unsigned int r = (u + 0x7FFFu + ((u >> 16) & 1u)) >> 16;  // RNE (inputs finite)
    return (unsigned short)r;
}

// Truncation split: hi = upper 16 bits of fp32 (exact bf16), lo = RNE-bf16 of
// the residual. A ~ Ah + Al with |Al| <= 2^-16|A|; 3-term product error ~2^-17.
static __device__ __forceinline__ void split2(float x, unsigned short& h, unsigned short& l) {
    unsigned int u = __float_as_uint(x);
    unsigned int hu = u & 0xFFFF0000u;
    h = (unsigned short)(hu >> 16);
    l = f2bu(x - __uint_as_float(hu));
}

// ---------------------------------------------------------------------------
// Kernel 1: copy K_past/V_past (fp32) into first TP_ rows of K_out/V_out.
// ---------------------------------------------------------------------------
__global__ __launch_bounds__(256) void copy_past_kernel(
    const float* __restrict__ Kp, const float* __restrict__ Vp,
    float* __restrict__ Ko, float* __restrict__ Vo)
{
    const long long NV = (long long)B_ * H_ * TP_ * D_ / 4;  // 8388608 float4 per tensor
    long long stride = (long long)gridDim.x * blockDim.x;
    for (long long idx = (long long)blockIdx.x * blockDim.x + threadIdx.x;
         idx < 2 * NV; idx += stride) {
        int sel = idx >= NV;
        long long v = sel ? idx - NV : idx;
        long long bh = v >> 16;        // / (TP_*D_/4 = 65536)
        long long r  = v & 65535;
        const float4* s = (const float4*)((sel ? Vp : Kp) + (bh << 18)) + r;
        float4* d = (float4*)((sel ? Vo : Ko) + bh * (long long)(TT_ * D_)) + r;
        *d = *s;
    }
}

// ---------------------------------------------------------------------------
// Kernel 2: split-bf16 MFMA GEMM  out[1024,2048] = A[1024,2048]@W[2048,2048]+b
// 3-term Markidis: Ah*Wh + Al*Wh + Ah*Wl, fp32 MFMA accumulate (~2^-17 rel).
// Tile 64x128, BK=64, 4 waves (2m x 2n), wave tile 32x64 (acc f32x4[2][4]).
// LDS rows padded to 72 ushorts (144 B): all b128 frag reads and ushort4
// staging writes are <=2-way per phase (36 = 4 mod 32).
// grid = (M/64, N/128); consecutive blockIdx.x share the W panel (L2 reuse).
// scatter=0: row-major out; scatter=1: write into KV cache rows TP_..TP_+127.
// ---------------------------------------------------------------------------
__global__ __launch_bounds__(256) void gemm_kernel(
    const float* __restrict__ A,
    const float* __restrict__ W,
    const float* __restrict__ bias,
    float* __restrict__ out,
    int scatter)
{
    __shared__ __align__(16) unsigned short Ah[64][72], Al[64][72];    // 9216 B each
    __shared__ __align__(16) unsigned short Bh[128][72], Bl[128][72];  // 18432 B each

    const int tid = threadIdx.x;
    const int m0 = blockIdx.x * 64, n0 = blockIdx.y * 128;

    // staging roles
    const int ar = tid >> 2;              // A row 0..63
    const int ak = (tid & 3) * 16;        // A k-base
    const int bn = tid & 127;             // B (W) column within tile
    const int bkh = (tid >> 7) * 32;      // B k-base (0 or 32)

    // compute roles
    const int lane = tid & 63, w = tid >> 6;
    const int lr = lane & 15, lg = lane >> 4;
    const int wm = (w >> 1) * 32, wn = (w & 1) * 64;

    f32x4 acc[2][4];
    #pragma unroll
    for (int i = 0; i < 2; ++i)
        #pragma unroll
        for (int j = 0; j < 4; ++j) acc[i][j] = (f32x4){0.f, 0.f, 0.f, 0.f};

    for (int kt = 0; kt < C_; kt += 64) {
        __syncthreads();
        // ---- stage A tile (64 m x 64 k), float4 coalesced, split hi/lo
        {
            const float4* ap = (const float4*)(A + (long long)(m0 + ar) * C_ + kt + ak);
            #pragma unroll
            for (int j = 0; j < 4; ++j) {
                float4 x = ap[j];
                ushort4 h4, l4;
                split2(x.x, h4.x, l4.x); split2(x.y, h4.y, l4.y);
                split2(x.z, h4.z, l4.z); split2(x.w, h4.w, l4.w);
                *(ushort4*)&Ah[ar][ak + j * 4] = h4;
                *(ushort4*)&Al[ar][ak + j * 4] = l4;
            }
        }
        // ---- stage W tile transposed (Bs[n][k]), coalesced column reads
        {
            const float* wp = W + (long long)(kt + bkh) * C_ + n0 + bn;
            #pragma unroll
            for (int j = 0; j < 8; ++j) {
                float x0 = wp[(j * 4 + 0) * C_];
                float x1 = wp[(j * 4 + 1) * C_];
                float x2 = wp[(j * 4 + 2) * C_];
                float x3 = wp[(j * 4 + 3) * C_];
                ushort4 h4, l4;
                split2(x0, h4.x, l4.x); split2(x1, h4.y, l4.y);
                split2(x2, h4.z, l4.z); split2(x3, h4.w, l4.w);
                *(ushort4*)&Bh[bn][bkh + j * 4] = h4;
                *(ushort4*)&Bl[bn][bkh + j * 4] = l4;
            }
        }
        __syncthreads();

        // ---- MFMA: 2 k-steps of 32
        #pragma unroll
        for (int ks = 0; ks < 2; ++ks) {
            const int ko = ks * 32 + lg * 8;
            bf16x8 ah0 = *(const bf16x8*)&Ah[wm + lr][ko];
            bf16x8 ah1 = *(const bf16x8*)&Ah[wm + 16 + lr][ko];
            bf16x8 al0 = *(const bf16x8*)&Al[wm + lr][ko];
            bf16x8 al1 = *(const bf16x8*)&Al[wm + 16 + lr][ko];
            #pragma unroll
            for (int nt = 0; nt < 4; ++nt) {
                bf16x8 bh = *(const bf16x8*)&Bh[wn + nt * 16 + lr][ko];
                bf16x8 bl = *(const bf16x8*)&Bl[wn + nt * 16 + lr][ko];
                acc[0][nt] = __builtin_amdgcn_mfma_f32_16x16x32_bf16(ah0, bh, acc[0][nt], 0, 0, 0);
                acc[0][nt] = __builtin_amdgcn_mfma_f32_16x16x32_bf16(al0, bh, acc[0][nt], 0, 0, 0);
                acc[0][nt] = __builtin_amdgcn_mfma_f32_16x16x32_bf16(ah0, bl, acc[0][nt], 0, 0, 0);
                acc[1][nt] = __builtin_amdgcn_mfma_f32_16x16x32_bf16(ah1, bh, acc[1][nt], 0, 0, 0);
                acc[1][nt] = __builtin_amdgcn_mfma_f32_16x16x32_bf16(al1, bh, acc[1][nt], 0, 0, 0);
                acc[1][nt] = __builtin_amdgcn_mfma_f32_16x16x32_bf16(ah1, bl, acc[1][nt], 0, 0, 0);
            }
        }
    }

    // ---- epilogue: bias + store (C/D map: col n = lane&15, row m = lg*4+r)
    #pragma unroll
    for (int nt = 0; nt < 4; ++nt) {
        const int n = n0 + wn + nt * 16 + lr;
        const float bb = bias[n];
        #pragma unroll
        for (int mt = 0; mt < 2; ++mt) {
            #pragma unroll
            for (int r = 0; r < 4; ++r) {
                const int m = m0 + wm + mt * 16 + lg * 4 + r;
                float v = acc[mt][nt][r] + bb;
                if (!scatter) {
                    out[(long long)m * C_ + n] = v;
                } else {
                    int b2 = m >> 7, t = m & 127, h2 = n >> 7, d2 = n & 127;
                    out[(((long long)(b2 * H_ + h2)) * TT_ + TP_ + t) * D_ + d2] = v;
                }
            }
        }
    }
}

// ---------------------------------------------------------------------------
// Kernel 3: MFMA flash attention (unchanged from verified round-1 version).
// ---------------------------------------------------------------------------
__global__ __launch_bounds__(256) void attn_mfma_kernel(
    const float* __restrict__ Qw,   // (1024, 2048): row b*128+t, col h*128+d
    const float* __restrict__ Kf,   // (B*H, 2176, 128) fp32
    const float* __restrict__ Vf,
    float* __restrict__ Ow,         // (1024, 2048)
    const int* __restrict__ poff)
{
    __shared__ __align__(16) unsigned short Ks[64][136];   // 17408 B
    __shared__ __align__(16) unsigned short Vt[128][72];   // 18432 B
    __shared__ __align__(16) unsigned short Pw[4][16][72]; //  9216 B

    const int tid = threadIdx.x;
    const int lane = tid & 63;
    const int w = tid >> 6;          // wave id 0..3
    const int lr = lane & 15;
    const int lg = lane >> 4;        // 0..3
    const int bh = blockIdx.x, b = bh >> 4, h = bh & 15;
    const int q0 = blockIdx.y * 64;
    const int off = *poff;
    const float scale = 0.08838834764831843f;  // 1/sqrt(128)

    // ---- Q A-fragments in registers: lane feeds row q=lr, dims kt*32+lg*8+0..7
    bf16x8 qf[4];
    {
        const float* qsrc = Qw + ((long long)(b * TN_ + q0 + w * 16 + lr)) * C_ + h * D_;
        #pragma unroll
        for (int kt = 0; kt < 4; ++kt) {
            const float4* p4 = (const float4*)(qsrc + kt * 32 + lg * 8);
            float4 x0 = p4[0], x1 = p4[1];
            union { unsigned short u[8]; bf16x8 v; } pk;
            pk.u[0] = f2bu(x0.x); pk.u[1] = f2bu(x0.y);
            pk.u[2] = f2bu(x0.z); pk.u[3] = f2bu(x0.w);
            pk.u[4] = f2bu(x1.x); pk.u[5] = f2bu(x1.y);
            pk.u[6] = f2bu(x1.z); pk.u[7] = f2bu(x1.w);
            qf[kt] = pk.v;
        }
    }

    const int skey = tid >> 2, sdg = (tid & 3) * 32;  // K staging: key row, dim group
    const int vd = tid & 127, vhalf = tid >> 7;       // V staging: dim, key half
    const int vswz = (vd >> 3) & 7;
    const int tq = q0 + w * 16 + lg * 4;              // this lane's D-row base (q)

    float m_r[4], l_r[4];
    f32x4 ov[8];
    #pragma unroll
    for (int r = 0; r < 4; ++r) { m_r[r] = -1e30f; l_r[r] = 0.f; }
    #pragma unroll
    for (int dt = 0; dt < 8; ++dt) ov[dt] = (f32x4){0.f, 0.f, 0.f, 0.f};

    const int upper = TP_ + q0 + 64;   // 64-aligned: no staging guards needed

    for (int kc = 0; kc < upper; kc += 64) {
        __syncthreads();   // prev chunk's PV reads done before restaging
        // ---- stage K chunk (row-major bf16, padded)
        {
            const float4* ksrc = (const float4*)(Kf + ((long long)bh * TT_ + kc + skey) * D_ + sdg);
            #pragma unroll
            for (int u = 0; u < 8; ++u) {
                float4 k4 = ksrc[u];
                ushort4 kp;
                kp.x = f2bu(k4.x); kp.y = f2bu(k4.y); kp.z = f2bu(k4.z); kp.w = f2bu(k4.w);
                *(ushort4*)&Ks[skey][sdg + u * 4] = kp;
            }
        }
        // ---- stage V chunk transposed: Vt[d][key], oct-XOR swizzle on key octets
        {
            const float* vsrc = Vf + ((long long)bh * TT_ + kc) * D_ + vd;
            #pragma unroll
            for (int j = 0; j < 8; ++j) {
                int k4 = vhalf * 32 + j * 4;
                float a0 = vsrc[(k4 + 0) * D_];
                float a1 = vsrc[(k4 + 1) * D_];
                float a2 = vsrc[(k4 + 2) * D_];
                float a3 = vsrc[(k4 + 3) * D_];
                ushort4 vp;
                vp.x = f2bu(a0); vp.y = f2bu(a1); vp.z = f2bu(a2); vp.w = f2bu(a3);
                int col = (((k4 >> 3) ^ vswz) << 3) + (k4 & 7);
                *(ushort4*)&Vt[vd][col] = vp;
            }
        }
        __syncthreads();

        // ---- QK^T: 4 key tiles x 4 k-steps
        f32x4 sa[4];
        #pragma unroll
        for (int n = 0; n < 4; ++n) {
            f32x4 acc = (f32x4){0.f, 0.f, 0.f, 0.f};
            #pragma unroll
            for (int kt = 0; kt < 4; ++kt) {
                bf16x8 kfrag = *(const bf16x8*)&Ks[n * 16 + lr][kt * 32 + lg * 8];
                acc = __builtin_amdgcn_mfma_f32_16x16x32_bf16(qf[kt], kfrag, acc, 0, 0, 0);
            }
            sa[n] = acc;
        }

        // ---- mask + scale (lane element (n,r): key=kc+n*16+lr, query=tq+r)
        float sv[4][4];
        #pragma unroll
        for (int n = 0; n < 4; ++n) {
            int kg = kc + n * 16 + lr;
            #pragma unroll
            for (int r = 0; r < 4; ++r) {
                bool okm = (kg < TP_) ? (kg <= off + tq + r) : (kg - TP_ <= tq + r);
                sv[n][r] = okm ? sa[n][r] * scale : -1e30f;
            }
        }

        // ---- online softmax per row; write P (bf16) to per-wave LDS
        #pragma unroll
        for (int r = 0; r < 4; ++r) {
            float mloc = fmaxf(fmaxf(sv[0][r], sv[1][r]), fmaxf(sv[2][r], sv[3][r]));
            #pragma unroll
            for (int dx = 1; dx < 16; dx <<= 1) mloc = fmaxf(mloc, __shfl_xor(mloc, dx));
            float mnew = fmaxf(m_r[r], mloc);
            float alpha = __expf(m_r[r] - mnew);   // first chunk: exp(-inf)=0
            float psum = 0.f;
            #pragma unroll
            for (int n = 0; n < 4; ++n) {
                float p = __expf(sv[n][r] - mnew); // masked: exp(-1e30)==0
                psum += p;
                Pw[w][lg * 4 + r][n * 16 + lr] = f2bu(p);
            }
            #pragma unroll
            for (int dx = 1; dx < 16; dx <<= 1) psum += __shfl_xor(psum, dx);
            m_r[r] = mnew;
            l_r[r] = l_r[r] * alpha + psum;
            #pragma unroll
            for (int dt = 0; dt < 8; ++dt) ov[dt][r] *= alpha;
        }

        // ---- PV: A = P fragments (row q=lr, keys lg*8+..), B = Vt rows
        bf16x8 pf0 = *(const bf16x8*)&Pw[w][lr][lg * 8];
        bf16x8 pf1 = *(const bf16x8*)&Pw[w][lr][32 + lg * 8];
        #pragma unroll
        for (int dt = 0; dt < 8; ++dt) {
            int d = dt * 16 + lr;
            int sw = (d >> 3) & 7;
            bf16x8 vf0 = *(const bf16x8*)&Vt[d][(lg ^ sw) << 3];
            ov[dt] = __builtin_amdgcn_mfma_f32_16x16x32_bf16(pf0, vf0, ov[dt], 0, 0, 0);
            bf16x8 vf1 = *(const bf16x8*)&Vt[d][((4 + lg) ^ sw) << 3];
            ov[dt] = __builtin_amdgcn_mfma_f32_16x16x32_bf16(pf1, vf1, ov[dt], 0, 0, 0);
        }
    }

    // ---- epilogue: normalize and store
    #pragma unroll
    for (int r = 0; r < 4; ++r) {
        float inv = 1.0f / l_r[r];
        float* dst = Ow + ((long long)(b * TN_ + tq + r)) * C_ + h * D_ + lr;
        #pragma unroll
        for (int dt = 0; dt < 8; ++dt) dst[dt * 16] = ov[dt][r] * inv;
    }
}

// ---------------------------------------------------------------------------
extern "C" void kernel_launch(void* const* d_in, const int* in_sizes, int n_in,
                              void* d_out, int out_size, void* d_ws, size_t ws_size,
                              hipStream_t stream)
{
    (void)in_sizes; (void)n_in; (void)out_size; (void)ws_size;
    const float* x  = (const float*)d_in[0];
    const float* Kp = (const float*)d_in[1];
    const float* Vp = (const float*)d_in[2];
    const float* Wq = (const float*)d_in[3];
    const float* bq = (const float*)d_in[4];
    const float* Wk = (const float*)d_in[5];
    const float* bk = (const float*)d_in[6];
    const float* Wv = (const float*)d_in[7];
    const float* bv = (const float*)d_in[8];
    const float* Wo = (const float*)d_in[9];
    const float* bo = (const float*)d_in[10];
    const int* poff = (const int*)d_in[11];

    float* out = (float*)d_out;
    float* Ko  = out + (long long)M_ * C_;                 // K output region
    float* Vo  = Ko + (long long)B_ * H_ * TT_ * D_;       // V output region

    float* Qws = (float*)d_ws;                             // 8 MB: Q (1024x2048 f32)
    float* Aws = Qws + (long long)M_ * C_;                 // 8 MB: attn out

    hipLaunchKernelGGL(copy_past_kernel, dim3(8192), dim3(256), 0, stream, Kp, Vp, Ko, Vo);
    dim3 gg(M_ / 64, C_ / 128);   // x = m-blocks: consecutive ids share W panel
    hipLaunchKernelGGL(gemm_kernel, gg, dim3(256), 0, stream, x, Wq, bq, Qws, 0);
    hipLaunchKernelGGL(gemm_kernel, gg, dim3(256), 0, stream, x, Wk, bk, Ko, 1);
    hipLaunchKernelGGL(gemm_kernel, gg, dim3(256), 0, stream, x, Wv, bv, Vo, 1);
    hipLaunchKernelGGL(attn_mfma_kernel, dim3(B_ * H_, TN_ / 64), dim3(256), 0, stream,
                       Qws, Ko, Vo, Aws, poff);
    hipLaunchKernelGGL(gemm_kernel, gg, dim3(256), 0, stream, Aws, Wo, bo, out, 0);
}